// Round 9
// baseline (106.621 us; speedup 1.0000x reference)
//
#include <hip/hip_runtime.h>
#include <hip/hip_bf16.h>

typedef __attribute__((ext_vector_type(8))) short short8;
typedef __attribute__((ext_vector_type(4))) short short4v;
typedef __attribute__((ext_vector_type(4))) float float4v;
typedef __attribute__((ext_vector_type(4))) int int4v;

#define MFMA16(a,b,c) __builtin_amdgcn_mfma_f32_16x16x32_bf16((a),(b),(c),0,0,0)
#define EXP2(x) __builtin_amdgcn_exp2f(x)

static constexpr int Bz = 16, Sq = 1024, Dm = 384, Hh = 6, Dh = 64;
static constexpr int Mtok = Bz * Sq;     // 16384
static constexpr int NQKV = 1152;        // 3 * H * DH

__device__ __forceinline__ short f2bf(float f) {
  union { float f; unsigned u; } v; v.f = f;
  unsigned r = v.u + 0x7fffu + ((v.u >> 16) & 1u);  // RNE
  return (short)(r >> 16);
}

// packed f32x2 -> bf16x2 (lo = a, hi = b), RNE in HW
__device__ __forceinline__ unsigned cvtpk(float a, float b) {
  unsigned d;
  asm("v_cvt_pk_bf16_f32 %0, %1, %2" : "=v"(d) : "v"(a), "v"(b));
  return d;
}

__device__ __forceinline__ void gload16(const void* src, void* lds) {
  __builtin_amdgcn_global_load_lds(
      (const __attribute__((address_space(1))) unsigned int*)src,
      (__attribute__((address_space(3))) unsigned int*)lds, 16, 0, 0);
}

// kv-permutation within each 32-block: loc = 16hi+4grp+e -> 8grp+4hi+e.
// Makes each lane's PV B-fragment 16 CONTIGUOUS bytes -> single
// conflict-free ds_read_b128 in attn (verified R7: conflicts -> 0).
__device__ __forceinline__ int vperm(int s) {
  return (s & ~31) | ((s & 12) << 1) | ((s & 16) >> 2) | (s & 3);
}

// ---------------- prep: x fp32 -> bf16 ----------------
__global__ __launch_bounds__(256) void conv_x(const float* __restrict__ x,
                                              short* __restrict__ xb) {
  const int i = (blockIdx.x * 256 + threadIdx.x) * 8;  // total 6291456, exact
  float4v v0 = *(const float4v*)(x + i);
  float4v v1 = *(const float4v*)(x + i + 4);
  short8 o;
  o[0] = f2bf(v0[0]); o[1] = f2bf(v0[1]); o[2] = f2bf(v0[2]); o[3] = f2bf(v0[3]);
  o[4] = f2bf(v1[0]); o[5] = f2bf(v1[1]); o[6] = f2bf(v1[2]); o[7] = f2bf(v1[3]);
  *(short8*)(xb + i) = o;
}

// ---------------- prep: weights ----------------
__global__ __launch_bounds__(256) void conv_w(const float* __restrict__ Wq,
                                              const float* __restrict__ Wk,
                                              const float* __restrict__ Wv,
                                              const float* __restrict__ bq,
                                              const float* __restrict__ bk,
                                              const float* __restrict__ bv,
                                              const float* __restrict__ Wo,
                                              short* __restrict__ Wt,
                                              float* __restrict__ bias,
                                              short* __restrict__ Wob) {
  const float SCL = 0.125f * 1.44269504088896340736f;
  const int i = blockIdx.x * 256 + threadIdx.x;
  const int NW = NQKV * Dm;            // 442368
  if (i < NW) {
    const int c = i / Dm, d = i % Dm;
    const int p = c / 384, rr = c % 384;
    const int h = rr >> 6, dh = rr & 63;
    const float* W = (p == 0) ? Wq : ((p == 1) ? Wk : Wv);
    float w = W[(h * Dm + d) * Dh + dh];
    if (p == 0) w *= SCL;
    Wt[c * Dm + d] = f2bf(w);
  } else if (i < NW + NQKV) {
    const int c = i - NW;
    const int p = c / 384, rr = c % 384;
    const int h = rr >> 6, dh = rr & 63;
    const float* bb = (p == 0) ? bq : ((p == 1) ? bk : bv);
    float b = bb[h * Dh + dh];
    if (p == 0) b *= SCL;
    bias[c] = b;
  } else if (i < NW + NQKV + Dm * Dm) {
    const int j = i - NW - NQKV;
    Wob[j] = f2bf(Wo[j]);
  }
}

// ---------------- QKV GEMM v6: BK=32, 1-barrier 3-buf ----------------
__global__ __launch_bounds__(256) void qkv_gemm(const short* __restrict__ Xb,
                                                const short* __restrict__ Wt,
                                                const float* __restrict__ bias,
                                                short* __restrict__ qkv,
                                                short* __restrict__ vt) {
  __shared__ char smem[49152];  // 3 bufs x (8KB A + 8KB B)
  const int tid = threadIdx.x;
  const int wave = tid >> 6, lane = tid & 63;
  const int r = lane & 15, g = lane >> 4;
  const int wr = wave >> 1, wc = wave & 1;

  // XCD-chunked bijective swizzle: nwg = 1152 = 8*144
  const int flat = blockIdx.x;
  const int w = (flat & 7) * 144 + (flat >> 3);
  const int bx = w % 9, by = w / 9;
  const int bm0 = by * 128, bn0 = bx * 128;
  const int m0 = bm0 + wr * 64, n0 = bn0 + wc * 64;

  float bv_n[4];
#pragma unroll
  for (int ni = 0; ni < 4; ++ni) bv_n[ni] = bias[n0 + ni * 16 + r];
  asm volatile("s_waitcnt vmcnt(0)" ::: "memory");

  const char *aSrc0, *aSrc1, *bSrc0, *bSrc1;
  {
    const int o0 = tid * 16, o1 = 4096 + tid * 16;
    const int lr0 = o0 >> 7, cb0 = (o0 & 127) ^ ((lr0 & 7) << 4);
    const int lr1 = o1 >> 7, cb1 = (o1 & 127) ^ ((lr1 & 7) << 4);
    const int m_0 = 2 * lr0 + (cb0 >> 6), kb0 = cb0 & 63;
    const int m_1 = 2 * lr1 + (cb1 >> 6), kb1 = cb1 & 63;
    aSrc0 = (const char*)(Xb + (bm0 + m_0) * Dm) + kb0;
    aSrc1 = (const char*)(Xb + (bm0 + m_1) * Dm) + kb1;
    bSrc0 = (const char*)(Wt + (bn0 + m_0) * Dm) + kb0;
    bSrc1 = (const char*)(Wt + (bn0 + m_1) * Dm) + kb1;
  }
  auto stage = [&](int t, int buf) {
    char* base = smem + buf * 16384;
    const int kb = t * 64;
    gload16(aSrc0 + kb, base + wave * 1024);
    gload16(aSrc1 + kb, base + 4096 + wave * 1024);
    gload16(bSrc0 + kb, base + 8192 + wave * 1024);
    gload16(bSrc1 + kb, base + 12288 + wave * 1024);
  };

  int aOff[4], bOff[4];
#pragma unroll
  for (int i = 0; i < 4; ++i) {
    const int m = wr * 64 + i * 16 + r;
    const int lr = m >> 1;
    aOff[i] = lr * 128 + ((((m & 1) << 6) | (16 * g)) ^ ((lr & 7) << 4));
    const int n = wc * 64 + i * 16 + r;
    const int lrn = n >> 1;
    bOff[i] = 8192 + lrn * 128 + ((((n & 1) << 6) | (16 * g)) ^ ((lrn & 7) << 4));
  }

  float4v acc[4][4] = {};
  auto compute = [&](int buf) {
    const char* sb = smem + buf * 16384;
    short8 a[4], b[4];
#pragma unroll
    for (int i = 0; i < 4; ++i) a[i] = *(const short8*)(sb + aOff[i]);
#pragma unroll
    for (int i = 0; i < 4; ++i) b[i] = *(const short8*)(sb + bOff[i]);
#pragma unroll
    for (int mi = 0; mi < 4; ++mi)
#pragma unroll
      for (int ni = 0; ni < 4; ++ni)
        acc[mi][ni] = MFMA16(a[mi], b[ni], acc[mi][ni]);
  };

  stage(0, 0);
  stage(1, 1);
#pragma unroll 1
  for (int t = 0; t < 10; ++t) {  // 12 K-steps total
    asm volatile("s_waitcnt vmcnt(4)" ::: "memory");
    __builtin_amdgcn_s_barrier();
    compute(t % 3);
    stage(t + 2, (t + 2) % 3);
  }
  asm volatile("s_waitcnt vmcnt(4)" ::: "memory");
  __builtin_amdgcn_s_barrier();
  compute(1);
  asm volatile("s_waitcnt vmcnt(0)" ::: "memory");
  __builtin_amdgcn_s_barrier();
  compute(2);

#pragma unroll
  for (int ni = 0; ni < 4; ++ni) {
    const int col = n0 + ni * 16 + r;
    const int p = col / 384, rr2 = col % 384;
    const int h = rr2 >> 6, dh = rr2 & 63;
    const float bv = bv_n[ni];
#pragma unroll
    for (int mi = 0; mi < 4; ++mi) {
#pragma unroll
      for (int rp = 0; rp < 2; ++rp) {
        const unsigned u = cvtpk(acc[mi][ni][2 * rp] + bv,
                                 acc[mi][ni][2 * rp + 1] + bv);
        const int mg = m0 + mi * 16 + 4 * g + 2 * rp;
        if (p < 2) {
          qkv[mg * NQKV + col] = (short)u;
          qkv[(mg + 1) * NQKV + col] = (short)(u >> 16);
        } else {
          const int bb = mg >> 10, s = mg & 1023;
          const int sp = vperm(s);  // sp even -> 4B-aligned int store
          short* vp = vt + ((bb * Hh + h) * Dh + dh) * Sq;
          *(unsigned*)(vp + sp) = u;
        }
      }
    }
  }
}

// ---------------- attention v8: 16 q-rows/wave, grid 1536, occupancy 5 blk/CU --
// 4 waves x 16 q-rows; KBLK=64; 2-buf 32KB LDS (5 blocks/CU = 160KB exact);
// fp32 denominator (R7-proven numerics); permuted-V single ds_read_b128.
__global__ __launch_bounds__(256, 5) void attn(const short* __restrict__ qkv,
                                               const short* __restrict__ vt,
                                               short* __restrict__ ctx) {
  __shared__ char smem[32768];  // 2 bufs x (8KB K + 8KB V)
  const int tid = threadIdx.x;
  const int wave = tid >> 6, lane = tid & 63;
  const int r = lane & 15, g = lane >> 4;
  const int xr = (r & 7) << 4;
  // XCD-chunked swizzle: nwg = 1536 = 8*192
  const int flat = blockIdx.x;
  const int w = (flat & 7) * 192 + (flat >> 3);
  const int qb = w & 15, bh = w >> 4;
  const int b = bh / Hh, h = bh % Hh;
  const int tok0 = b * Sq;
  const int qw = qb * 64 + wave * 16;

  const short* qp = qkv + (tok0 + qw + r) * NQKV + h * Dh;
  const short8 qf0 = *(const short8*)(qp + 8 * g);
  const short8 qf1 = *(const short8*)(qp + 32 + 8 * g);
  asm volatile("s_waitcnt vmcnt(0)" ::: "memory");  // drain Q before DMA counting

  const short* kg = qkv + tok0 * NQKV + 384 + h * Dh;  // K rows, stride NQKV
  const short* vg = vt + (b * Hh + h) * Dh * Sq;       // V^T rows (kv-permuted)

  const int o0 = wave * 2048 + lane * 16;
  const int row0 = o0 >> 7, cb0 = (o0 & 127) ^ ((row0 & 7) << 4);
  const int o1 = o0 + 1024;
  const int row1 = o1 >> 7, cb1 = (o1 & 127) ^ ((row1 & 7) << 4);

#define STAGE(T, BUFSEL)                                                        \
  {                                                                             \
    char* kb_ = smem + (BUFSEL) * 16384;                                        \
    const int kv_ = (T) * 64;                                                   \
    gload16((const char*)(kg + (kv_ + row0) * NQKV) + cb0, kb_ + wave * 2048);  \
    gload16((const char*)(vg + row0 * Sq + kv_) + cb0, kb_ + 8192 + wave * 2048);\
    gload16((const char*)(kg + (kv_ + row1) * NQKV) + cb1, kb_ + wave * 2048 + 1024);\
    gload16((const char*)(vg + row1 * Sq + kv_) + cb1, kb_ + 8192 + wave * 2048 + 1024);\
  }

  int kOff[4][2], vOff[4][2];
#pragma unroll
  for (int kt = 0; kt < 4; ++kt)
#pragma unroll
    for (int c = 0; c < 2; ++c)
      kOff[kt][c] = (16 * kt + r) * 128 + ((64 * c + 16 * g) ^ xr);
#pragma unroll
  for (int d = 0; d < 4; ++d)
#pragma unroll
    for (int h2 = 0; h2 < 2; ++h2)
      vOff[d][h2] = (16 * d + r) * 128 + ((64 * h2 + 16 * g) ^ xr);

  float4v acc[4] = {};
  float lsum = 0.f;

  auto compute = [&](int bufsel) {
    const char* kb = smem + bufsel * 16384;
    const char* vb = kb + 8192;
    short8 kf[4][2];
#pragma unroll
    for (int kt = 0; kt < 4; ++kt) {
      kf[kt][0] = *(const short8*)(kb + kOff[kt][0]);
      kf[kt][1] = *(const short8*)(kb + kOff[kt][1]);
    }
    short8 vf[4][2];
#pragma unroll
    for (int d = 0; d < 4; ++d)
#pragma unroll
      for (int h2 = 0; h2 < 2; ++h2)
        vf[d][h2] = *(const short8*)(vb + vOff[d][h2]);
    float4v s[4];
    __builtin_amdgcn_s_setprio(1);
#pragma unroll
    for (int kt = 0; kt < 4; ++kt) {
      float4v z = {};
      z = MFMA16(kf[kt][0], qf0, z);
      z = MFMA16(kf[kt][1], qf1, z);
      s[kt] = z;
    }
    __builtin_amdgcn_s_setprio(0);
    short8 pa[2];
    float ps = 0.f;
#pragma unroll
    for (int h2 = 0; h2 < 2; ++h2) {
      float e0[4], e1[4];
#pragma unroll
      for (int j = 0; j < 4; ++j) {
        e0[j] = EXP2(s[2 * h2][j]);
        e1[j] = EXP2(s[2 * h2 + 1][j]);
        ps += e0[j] + e1[j];
      }
      int4v wv;
      wv[0] = (int)cvtpk(e0[0], e0[1]);
      wv[1] = (int)cvtpk(e0[2], e0[3]);
      wv[2] = (int)cvtpk(e1[0], e1[1]);
      wv[3] = (int)cvtpk(e1[2], e1[3]);
      pa[h2] = __builtin_bit_cast(short8, wv);
    }
    lsum += ps;
    __builtin_amdgcn_s_setprio(1);
#pragma unroll
    for (int d = 0; d < 4; ++d) {
      acc[d] = MFMA16(pa[0], vf[d][0], acc[d]);
      acc[d] = MFMA16(pa[1], vf[d][1], acc[d]);
    }
    __builtin_amdgcn_s_setprio(0);
  };

  STAGE(0, 0)
  STAGE(1, 1)
#pragma unroll 1
  for (int t = 0; t < 15; ++t) {
    asm volatile("s_waitcnt vmcnt(4)" ::: "memory");
    __builtin_amdgcn_s_barrier();
    compute(t & 1);
    __builtin_amdgcn_s_barrier();
    if (t < 14) STAGE(t + 2, t & 1)
  }
  asm volatile("s_waitcnt vmcnt(0)" ::: "memory");
  __builtin_amdgcn_s_barrier();
  compute(1);

  lsum += __shfl_xor(lsum, 16);
  lsum += __shfl_xor(lsum, 32);
  float il[4];
#pragma unroll
  for (int reg = 0; reg < 4; ++reg) il[reg] = 1.f / __shfl(lsum, 4 * g + reg);
#pragma unroll
  for (int d = 0; d < 4; ++d) {
    short* cp = ctx + (tok0 + qw + 4 * g) * Dm + h * Dh + 16 * d + r;
#pragma unroll
    for (int reg = 0; reg < 4; ++reg)
      cp[reg * Dm] = f2bf(acc[d][reg] * il[reg]);
  }
}

// ---------------- out-proj GEMM v5: BK=32, 1-barrier 3-buf ----------------
__global__ __launch_bounds__(256) void out_gemm(const short* __restrict__ ctx,
                                                const short* __restrict__ Wob,
                                                const float* __restrict__ bo,
                                                float* __restrict__ out) {
  __shared__ char smem[49152];
  const int tid = threadIdx.x;
  const int wave = tid >> 6, lane = tid & 63;
  const int r = lane & 15, g = lane >> 4;
  const int wr = wave >> 1, wc = wave & 1;

  // XCD-chunked bijective swizzle: nwg = 384 = 8*48
  const int flat = blockIdx.x;
  const int w = (flat & 7) * 48 + (flat >> 3);
  const int bx = w % 3, by = w / 3;
  const int bm0 = by * 128, bn0 = bx * 128;
  const int m0 = bm0 + wr * 64, n0 = bn0 + wc * 64;

  float bv_n[4];
#pragma unroll
  for (int ni = 0; ni < 4; ++ni) bv_n[ni] = bo[n0 + ni * 16 + r];
  asm volatile("s_waitcnt vmcnt(0)" ::: "memory");

  const char *aSrc0, *aSrc1, *bSrc0, *bSrc1;
  {
    const int o0 = tid * 16, o1 = 4096 + tid * 16;
    const int lr0 = o0 >> 7, cb0 = (o0 & 127) ^ ((lr0 & 7) << 4);
    const int lr1 = o1 >> 7, cb1 = (o1 & 127) ^ ((lr1 & 7) << 4);
    const int m_0 = 2 * lr0 + (cb0 >> 6), kb0 = cb0 & 63;
    const int m_1 = 2 * lr1 + (cb1 >> 6), kb1 = cb1 & 63;
    aSrc0 = (const char*)(ctx + (bm0 + m_0) * Dm) + kb0;
    aSrc1 = (const char*)(ctx + (bm0 + m_1) * Dm) + kb1;
    bSrc0 = (const char*)(Wob + (bn0 + m_0) * Dm) + kb0;
    bSrc1 = (const char*)(Wob + (bn0 + m_1) * Dm) + kb1;
  }
  auto stage = [&](int t, int buf) {
    char* base = smem + buf * 16384;
    const int kb = t * 64;
    gload16(aSrc0 + kb, base + wave * 1024);
    gload16(aSrc1 + kb, base + 4096 + wave * 1024);
    gload16(bSrc0 + kb, base + 8192 + wave * 1024);
    gload16(bSrc1 + kb, base + 12288 + wave * 1024);
  };

  int aOff[4], bOff[4];
#pragma unroll
  for (int i = 0; i < 4; ++i) {
    const int m = wr * 64 + i * 16 + r;
    const int lr = m >> 1;
    aOff[i] = lr * 128 + ((((m & 1) << 6) | (16 * g)) ^ ((lr & 7) << 4));
    const int n = wc * 64 + i * 16 + r;
    const int lrn = n >> 1;
    bOff[i] = 8192 + lrn * 128 + ((((n & 1) << 6) | (16 * g)) ^ ((lrn & 7) << 4));
  }

  float4v acc[4][4] = {};
  auto compute = [&](int buf) {
    const char* sb = smem + buf * 16384;
    short8 a[4], b[4];
#pragma unroll
    for (int i = 0; i < 4; ++i) a[i] = *(const short8*)(sb + aOff[i]);
#pragma unroll
    for (int i = 0; i < 4; ++i) b[i] = *(const short8*)(sb + bOff[i]);
#pragma unroll
    for (int mi = 0; mi < 4; ++mi)
#pragma unroll
      for (int ni = 0; ni < 4; ++ni)
        acc[mi][ni] = MFMA16(a[mi], b[ni], acc[mi][ni]);
  };

  stage(0, 0);
  stage(1, 1);
#pragma unroll 1
  for (int t = 0; t < 10; ++t) {
    asm volatile("s_waitcnt vmcnt(4)" ::: "memory");
    __builtin_amdgcn_s_barrier();
    compute(t % 3);
    stage(t + 2, (t + 2) % 3);
  }
  asm volatile("s_waitcnt vmcnt(4)" ::: "memory");
  __builtin_amdgcn_s_barrier();
  compute(1);
  asm volatile("s_waitcnt vmcnt(0)" ::: "memory");
  __builtin_amdgcn_s_barrier();
  compute(2);

#pragma unroll
  for (int ni = 0; ni < 4; ++ni) {
    const int col = n0 + ni * 16 + r;
    const float bv = bv_n[ni];
#pragma unroll
    for (int mi = 0; mi < 4; ++mi) {
#pragma unroll
      for (int reg = 0; reg < 4; ++reg) {
        const int mg = m0 + mi * 16 + 4 * g + reg;
        out[mg * Dm + col] = acc[mi][ni][reg] + bv;
      }
    }
  }
}

extern "C" void kernel_launch(void* const* d_in, const int* in_sizes, int n_in,
                              void* d_out, int out_size, void* d_ws, size_t ws_size,
                              hipStream_t stream) {
  const float* x  = (const float*)d_in[0];
  const float* Wq = (const float*)d_in[1];
  const float* bq = (const float*)d_in[2];
  const float* Wk = (const float*)d_in[3];
  const float* bk = (const float*)d_in[4];
  const float* Wv = (const float*)d_in[5];
  const float* bv = (const float*)d_in[6];
  const float* Wo = (const float*)d_in[7];
  const float* bo = (const float*)d_in[8];
  float* out = (float*)d_out;

  char* ws = (char*)d_ws;
  short* Xb   = (short*)(ws);                  // 16384*384*2   = 12,582,912
  short* Wt   = (short*)(ws + 12582912);       // 1152*384*2    =    884,736
  float* bias = (float*)(ws + 13467648);       // 1152*4        =      4,608
  short* Wob  = (short*)(ws + 13472256);       // 384*384*2     =    294,912
  short* qkv  = (short*)(ws + 13767168);       // 16384*1152*2  = 37,748,736
  short* vt   = (short*)(ws + 51515904);       // 16*6*64*1024*2= 12,582,912
  short* ctx  = (short*)(ws + 64098816);       // 16384*384*2   = 12,582,912
  // total 76,681,728 bytes

  conv_x<<<Mtok * Dm / (256 * 8), 256, 0, stream>>>(x, Xb);
  conv_w<<<(NQKV * Dm + NQKV + Dm * Dm + 255) / 256, 256, 0, stream>>>(
      Wq, Wk, Wv, bq, bk, bv, Wo, Wt, bias, Wob);
  qkv_gemm<<<1152, 256, 0, stream>>>(Xb, Wt, bias, qkv, vt);
  attn<<<1536, 256, 0, stream>>>(qkv, vt, ctx);
  out_gemm<<<384, 256, 0, stream>>>(ctx, Wob, bo, out);
}

// Round 10
// 98.327 us; speedup vs baseline: 1.0843x; 1.0843x over previous
//
#include <hip/hip_runtime.h>
#include <hip/hip_bf16.h>

typedef __attribute__((ext_vector_type(8))) short short8;
typedef __attribute__((ext_vector_type(4))) short short4v;
typedef __attribute__((ext_vector_type(4))) float float4v;
typedef __attribute__((ext_vector_type(2))) float float2v;
typedef __attribute__((ext_vector_type(4))) int int4v;

#define MFMA16(a,b,c) __builtin_amdgcn_mfma_f32_16x16x32_bf16((a),(b),(c),0,0,0)
#define EXP2(x) __builtin_amdgcn_exp2f(x)

static constexpr int Bz = 16, Sq = 1024, Dm = 384, Hh = 6, Dh = 64;
static constexpr int Mtok = Bz * Sq;     // 16384
static constexpr int NQKV = 1152;        // 3 * H * DH

__device__ __forceinline__ short f2bf(float f) {
  union { float f; unsigned u; } v; v.f = f;
  unsigned r = v.u + 0x7fffu + ((v.u >> 16) & 1u);  // RNE
  return (short)(r >> 16);
}

// packed f32x2 -> bf16x2 (lo = a, hi = b), RNE in HW
__device__ __forceinline__ unsigned cvtpk(float a, float b) {
  unsigned d;
  asm("v_cvt_pk_bf16_f32 %0, %1, %2" : "=v"(d) : "v"(a), "v"(b));
  return d;
}

__device__ __forceinline__ void gload16(const void* src, void* lds) {
  __builtin_amdgcn_global_load_lds(
      (const __attribute__((address_space(1))) unsigned int*)src,
      (__attribute__((address_space(3))) unsigned int*)lds, 16, 0, 0);
}

// kv-permutation within each 32-block: loc = 16hi+4grp+e -> 8grp+4hi+e.
// Makes each lane's PV B-fragment 16 CONTIGUOUS bytes -> single
// conflict-free ds_read_b128 in attn (verified R7: conflicts -> 0).
__device__ __forceinline__ int vperm(int s) {
  return (s & ~31) | ((s & 12) << 1) | ((s & 16) >> 2) | (s & 3);
}

// ---------------- prep: x fp32 -> bf16 ----------------
__global__ __launch_bounds__(256) void conv_x(const float* __restrict__ x,
                                              short* __restrict__ xb) {
  const int i = (blockIdx.x * 256 + threadIdx.x) * 8;  // total 6291456, exact
  float4v v0 = *(const float4v*)(x + i);
  float4v v1 = *(const float4v*)(x + i + 4);
  short8 o;
  o[0] = f2bf(v0[0]); o[1] = f2bf(v0[1]); o[2] = f2bf(v0[2]); o[3] = f2bf(v0[3]);
  o[4] = f2bf(v1[0]); o[5] = f2bf(v1[1]); o[6] = f2bf(v1[2]); o[7] = f2bf(v1[3]);
  *(short8*)(xb + i) = o;
}

// ---------------- prep: weights ----------------
__global__ __launch_bounds__(256) void conv_w(const float* __restrict__ Wq,
                                              const float* __restrict__ Wk,
                                              const float* __restrict__ Wv,
                                              const float* __restrict__ bq,
                                              const float* __restrict__ bk,
                                              const float* __restrict__ bv,
                                              const float* __restrict__ Wo,
                                              short* __restrict__ Wt,
                                              float* __restrict__ bias,
                                              short* __restrict__ Wob) {
  const float SCL = 0.125f * 1.44269504088896340736f;
  const int i = blockIdx.x * 256 + threadIdx.x;
  const int NW = NQKV * Dm;            // 442368
  if (i < NW) {
    const int c = i / Dm, d = i % Dm;
    const int p = c / 384, rr = c % 384;
    const int h = rr >> 6, dh = rr & 63;
    const float* W = (p == 0) ? Wq : ((p == 1) ? Wk : Wv);
    float w = W[(h * Dm + d) * Dh + dh];
    if (p == 0) w *= SCL;
    Wt[c * Dm + d] = f2bf(w);
  } else if (i < NW + NQKV) {
    const int c = i - NW;
    const int p = c / 384, rr = c % 384;
    const int h = rr >> 6, dh = rr & 63;
    const float* bb = (p == 0) ? bq : ((p == 1) ? bk : bv);
    float b = bb[h * Dh + dh];
    if (p == 0) b *= SCL;
    bias[c] = b;
  } else if (i < NW + NQKV + Dm * Dm) {
    const int j = i - NW - NQKV;
    Wob[j] = f2bf(Wo[j]);
  }
}

// ---------------- QKV GEMM v6: BK=32, 1-barrier 3-buf ----------------
__global__ __launch_bounds__(256) void qkv_gemm(const short* __restrict__ Xb,
                                                const short* __restrict__ Wt,
                                                const float* __restrict__ bias,
                                                short* __restrict__ qkv,
                                                short* __restrict__ vt) {
  __shared__ char smem[49152];  // 3 bufs x (8KB A + 8KB B)
  const int tid = threadIdx.x;
  const int wave = tid >> 6, lane = tid & 63;
  const int r = lane & 15, g = lane >> 4;
  const int wr = wave >> 1, wc = wave & 1;

  // XCD-chunked bijective swizzle: nwg = 1152 = 8*144
  const int flat = blockIdx.x;
  const int w = (flat & 7) * 144 + (flat >> 3);
  const int bx = w % 9, by = w / 9;
  const int bm0 = by * 128, bn0 = bx * 128;
  const int m0 = bm0 + wr * 64, n0 = bn0 + wc * 64;

  float bv_n[4];
#pragma unroll
  for (int ni = 0; ni < 4; ++ni) bv_n[ni] = bias[n0 + ni * 16 + r];
  asm volatile("s_waitcnt vmcnt(0)" ::: "memory");

  const char *aSrc0, *aSrc1, *bSrc0, *bSrc1;
  {
    const int o0 = tid * 16, o1 = 4096 + tid * 16;
    const int lr0 = o0 >> 7, cb0 = (o0 & 127) ^ ((lr0 & 7) << 4);
    const int lr1 = o1 >> 7, cb1 = (o1 & 127) ^ ((lr1 & 7) << 4);
    const int m_0 = 2 * lr0 + (cb0 >> 6), kb0 = cb0 & 63;
    const int m_1 = 2 * lr1 + (cb1 >> 6), kb1 = cb1 & 63;
    aSrc0 = (const char*)(Xb + (bm0 + m_0) * Dm) + kb0;
    aSrc1 = (const char*)(Xb + (bm0 + m_1) * Dm) + kb1;
    bSrc0 = (const char*)(Wt + (bn0 + m_0) * Dm) + kb0;
    bSrc1 = (const char*)(Wt + (bn0 + m_1) * Dm) + kb1;
  }
  auto stage = [&](int t, int buf) {
    char* base = smem + buf * 16384;
    const int kb = t * 64;
    gload16(aSrc0 + kb, base + wave * 1024);
    gload16(aSrc1 + kb, base + 4096 + wave * 1024);
    gload16(bSrc0 + kb, base + 8192 + wave * 1024);
    gload16(bSrc1 + kb, base + 12288 + wave * 1024);
  };

  int aOff[4], bOff[4];
#pragma unroll
  for (int i = 0; i < 4; ++i) {
    const int m = wr * 64 + i * 16 + r;
    const int lr = m >> 1;
    aOff[i] = lr * 128 + ((((m & 1) << 6) | (16 * g)) ^ ((lr & 7) << 4));
    const int n = wc * 64 + i * 16 + r;
    const int lrn = n >> 1;
    bOff[i] = 8192 + lrn * 128 + ((((n & 1) << 6) | (16 * g)) ^ ((lrn & 7) << 4));
  }

  float4v acc[4][4] = {};
  auto compute = [&](int buf) {
    const char* sb = smem + buf * 16384;
    short8 a[4], b[4];
#pragma unroll
    for (int i = 0; i < 4; ++i) a[i] = *(const short8*)(sb + aOff[i]);
#pragma unroll
    for (int i = 0; i < 4; ++i) b[i] = *(const short8*)(sb + bOff[i]);
#pragma unroll
    for (int mi = 0; mi < 4; ++mi)
#pragma unroll
      for (int ni = 0; ni < 4; ++ni)
        acc[mi][ni] = MFMA16(a[mi], b[ni], acc[mi][ni]);
  };

  stage(0, 0);
  stage(1, 1);
#pragma unroll 1
  for (int t = 0; t < 10; ++t) {  // 12 K-steps total
    asm volatile("s_waitcnt vmcnt(4)" ::: "memory");
    __builtin_amdgcn_s_barrier();
    compute(t % 3);
    stage(t + 2, (t + 2) % 3);
  }
  asm volatile("s_waitcnt vmcnt(4)" ::: "memory");
  __builtin_amdgcn_s_barrier();
  compute(1);
  asm volatile("s_waitcnt vmcnt(0)" ::: "memory");
  __builtin_amdgcn_s_barrier();
  compute(2);

#pragma unroll
  for (int ni = 0; ni < 4; ++ni) {
    const int col = n0 + ni * 16 + r;
    const int p = col / 384, rr2 = col % 384;
    const int h = rr2 >> 6, dh = rr2 & 63;
    const float bv = bv_n[ni];
#pragma unroll
    for (int mi = 0; mi < 4; ++mi) {
#pragma unroll
      for (int rp = 0; rp < 2; ++rp) {
        const unsigned u = cvtpk(acc[mi][ni][2 * rp] + bv,
                                 acc[mi][ni][2 * rp + 1] + bv);
        const int mg = m0 + mi * 16 + 4 * g + 2 * rp;
        if (p < 2) {
          qkv[mg * NQKV + col] = (short)u;
          qkv[(mg + 1) * NQKV + col] = (short)(u >> 16);
        } else {
          const int bb = mg >> 10, s = mg & 1023;
          const int sp = vperm(s);  // sp even -> 4B-aligned int store
          short* vp = vt + ((bb * Hh + h) * Dh + dh) * Sq;
          *(unsigned*)(vp + sp) = u;
        }
      }
    }
  }
}

// ---------------- attention v9: R8 pipeline + fp32 denominator ----------------
// grid 768; 4 waves x 32 q-rows; KBLK=64; 3-buf 48KB LDS, ONE barrier/tile,
// vmcnt(4). Permuted-V single ds_read_b128 (0 conflicts). fp32 ps via packed
// float2 adds (v_pk_add_f32); end-of-kernel shuffle reduce (R7 numerics).
__global__ __launch_bounds__(256) void attn(const short* __restrict__ qkv,
                                            const short* __restrict__ vt,
                                            short* __restrict__ ctx) {
  __shared__ char smem[49152];  // 3 bufs x (8KB K + 8KB V)
  const int tid = threadIdx.x;
  const int wave = tid >> 6, lane = tid & 63;
  const int r = lane & 15, g = lane >> 4;
  const int xr = (r & 7) << 4;
  // XCD-chunked swizzle: nwg = 768 = 8*96
  const int flat = blockIdx.x;
  const int w = (flat & 7) * 96 + (flat >> 3);
  const int qb = w & 7, bh = w >> 3;
  const int b = bh / Hh, h = bh % Hh;
  const int tok0 = b * Sq;
  const int qw = qb * 128 + wave * 32;

  short8 qf[2][2];
#pragma unroll
  for (int f = 0; f < 2; ++f) {
    const short* qp = qkv + (tok0 + qw + 16 * f + r) * NQKV + h * Dh;
    qf[f][0] = *(const short8*)(qp + 8 * g);
    qf[f][1] = *(const short8*)(qp + 32 + 8 * g);
  }
  asm volatile("s_waitcnt vmcnt(0)" ::: "memory");  // drain Q before DMA counting

  const short* kg = qkv + tok0 * NQKV + 384 + h * Dh;  // K rows, stride NQKV
  const short* vg = vt + (b * Hh + h) * Dh * Sq;       // V^T rows (kv-permuted)

  const int o0 = wave * 2048 + lane * 16;
  const int row0 = o0 >> 7, cb0 = (o0 & 127) ^ ((row0 & 7) << 4);
  const int o1 = o0 + 1024;
  const int row1 = o1 >> 7, cb1 = (o1 & 127) ^ ((row1 & 7) << 4);

#define STAGE(T, BUFSEL)                                                        \
  {                                                                             \
    char* kb_ = smem + (BUFSEL) * 16384;                                        \
    const int kv_ = (T) * 64;                                                   \
    gload16((const char*)(kg + (kv_ + row0) * NQKV) + cb0, kb_ + wave * 2048);  \
    gload16((const char*)(vg + row0 * Sq + kv_) + cb0, kb_ + 8192 + wave * 2048);\
    gload16((const char*)(kg + (kv_ + row1) * NQKV) + cb1, kb_ + wave * 2048 + 1024);\
    gload16((const char*)(vg + row1 * Sq + kv_) + cb1, kb_ + 8192 + wave * 2048 + 1024);\
  }

  int kOff[4][2], vOff[4][2];
#pragma unroll
  for (int kt = 0; kt < 4; ++kt)
#pragma unroll
    for (int c = 0; c < 2; ++c)
      kOff[kt][c] = (16 * kt + r) * 128 + ((64 * c + 16 * g) ^ xr);
#pragma unroll
  for (int d = 0; d < 4; ++d)
#pragma unroll
    for (int h2 = 0; h2 < 2; ++h2)
      vOff[d][h2] = (16 * d + r) * 128 + ((64 * h2 + 16 * g) ^ xr);

  float4v acc[4][2] = {};
  float2v lsum2[2] = {};

  auto compute = [&](int bufsel) {
    const char* kb = smem + bufsel * 16384;
    const char* vb = kb + 8192;
    short8 kf[4][2];
#pragma unroll
    for (int kt = 0; kt < 4; ++kt) {
      kf[kt][0] = *(const short8*)(kb + kOff[kt][0]);
      kf[kt][1] = *(const short8*)(kb + kOff[kt][1]);
    }
    short8 vf[4][2];
#pragma unroll
    for (int d = 0; d < 4; ++d)
#pragma unroll
      for (int h2 = 0; h2 < 2; ++h2)
        vf[d][h2] = *(const short8*)(vb + vOff[d][h2]);
    float4v s[4][2];
    __builtin_amdgcn_s_setprio(1);
#pragma unroll
    for (int kt = 0; kt < 4; ++kt)
#pragma unroll
      for (int f = 0; f < 2; ++f) {
        float4v z = {};
        z = MFMA16(kf[kt][0], qf[f][0], z);
        z = MFMA16(kf[kt][1], qf[f][1], z);
        s[kt][f] = z;
      }
    __builtin_amdgcn_s_setprio(0);
    short8 pa[2][2];
#pragma unroll
    for (int f = 0; f < 2; ++f) {
      float2v ps2 = {};
#pragma unroll
      for (int h2 = 0; h2 < 2; ++h2) {
        float e0[4], e1[4];
#pragma unroll
        for (int j = 0; j < 4; ++j) {
          e0[j] = EXP2(s[2 * h2][f][j]);
          e1[j] = EXP2(s[2 * h2 + 1][f][j]);
        }
#pragma unroll
        for (int j = 0; j < 2; ++j) {
          float2v p0 = {e0[2 * j], e0[2 * j + 1]};
          float2v p1 = {e1[2 * j], e1[2 * j + 1]};
          ps2 += p0 + p1;  // v_pk_add_f32
        }
        int4v wv;
        wv[0] = (int)cvtpk(e0[0], e0[1]);
        wv[1] = (int)cvtpk(e0[2], e0[3]);
        wv[2] = (int)cvtpk(e1[0], e1[1]);
        wv[3] = (int)cvtpk(e1[2], e1[3]);
        pa[f][h2] = __builtin_bit_cast(short8, wv);
      }
      lsum2[f] += ps2;
    }
    __builtin_amdgcn_s_setprio(1);
#pragma unroll
    for (int d = 0; d < 4; ++d)
#pragma unroll
      for (int f = 0; f < 2; ++f) {
        acc[d][f] = MFMA16(pa[f][0], vf[d][0], acc[d][f]);
        acc[d][f] = MFMA16(pa[f][1], vf[d][1], acc[d][f]);
      }
    __builtin_amdgcn_s_setprio(0);
  };

  STAGE(0, 0)
  STAGE(1, 1)
#pragma unroll 1
  for (int t = 0; t < 14; ++t) {
    asm volatile("s_waitcnt vmcnt(4)" ::: "memory");
    __builtin_amdgcn_s_barrier();
    compute(t % 3);
    STAGE(t + 2, (t + 2) % 3)
  }
  asm volatile("s_waitcnt vmcnt(4)" ::: "memory");
  __builtin_amdgcn_s_barrier();
  compute(2);   // tile 14
  asm volatile("s_waitcnt vmcnt(0)" ::: "memory");
  __builtin_amdgcn_s_barrier();
  compute(0);   // tile 15

#pragma unroll
  for (int f = 0; f < 2; ++f) {
    float lsum = lsum2[f][0] + lsum2[f][1];
    lsum += __shfl_xor(lsum, 16);
    lsum += __shfl_xor(lsum, 32);
    float il[4];
#pragma unroll
    for (int reg = 0; reg < 4; ++reg) il[reg] = 1.f / __shfl(lsum, 4 * g + reg);
#pragma unroll
    for (int d = 0; d < 4; ++d) {
      short* cp = ctx + (tok0 + qw + 16 * f + 4 * g) * Dm + h * Dh + 16 * d + r;
#pragma unroll
      for (int reg = 0; reg < 4; ++reg)
        cp[reg * Dm] = f2bf(acc[d][f][reg] * il[reg]);
    }
  }
}

// ---------------- out-proj GEMM v5: BK=32, 1-barrier 3-buf ----------------
__global__ __launch_bounds__(256) void out_gemm(const short* __restrict__ ctx,
                                                const short* __restrict__ Wob,
                                                const float* __restrict__ bo,
                                                float* __restrict__ out) {
  __shared__ char smem[49152];
  const int tid = threadIdx.x;
  const int wave = tid >> 6, lane = tid & 63;
  const int r = lane & 15, g = lane >> 4;
  const int wr = wave >> 1, wc = wave & 1;

  // XCD-chunked bijective swizzle: nwg = 384 = 8*48
  const int flat = blockIdx.x;
  const int w = (flat & 7) * 48 + (flat >> 3);
  const int bx = w % 3, by = w / 3;
  const int bm0 = by * 128, bn0 = bx * 128;
  const int m0 = bm0 + wr * 64, n0 = bn0 + wc * 64;

  float bv_n[4];
#pragma unroll
  for (int ni = 0; ni < 4; ++ni) bv_n[ni] = bo[n0 + ni * 16 + r];
  asm volatile("s_waitcnt vmcnt(0)" ::: "memory");

  const char *aSrc0, *aSrc1, *bSrc0, *bSrc1;
  {
    const int o0 = tid * 16, o1 = 4096 + tid * 16;
    const int lr0 = o0 >> 7, cb0 = (o0 & 127) ^ ((lr0 & 7) << 4);
    const int lr1 = o1 >> 7, cb1 = (o1 & 127) ^ ((lr1 & 7) << 4);
    const int m_0 = 2 * lr0 + (cb0 >> 6), kb0 = cb0 & 63;
    const int m_1 = 2 * lr1 + (cb1 >> 6), kb1 = cb1 & 63;
    aSrc0 = (const char*)(ctx + (bm0 + m_0) * Dm) + kb0;
    aSrc1 = (const char*)(ctx + (bm0 + m_1) * Dm) + kb1;
    bSrc0 = (const char*)(Wob + (bn0 + m_0) * Dm) + kb0;
    bSrc1 = (const char*)(Wob + (bn0 + m_1) * Dm) + kb1;
  }
  auto stage = [&](int t, int buf) {
    char* base = smem + buf * 16384;
    const int kb = t * 64;
    gload16(aSrc0 + kb, base + wave * 1024);
    gload16(aSrc1 + kb, base + 4096 + wave * 1024);
    gload16(bSrc0 + kb, base + 8192 + wave * 1024);
    gload16(bSrc1 + kb, base + 12288 + wave * 1024);
  };

  int aOff[4], bOff[4];
#pragma unroll
  for (int i = 0; i < 4; ++i) {
    const int m = wr * 64 + i * 16 + r;
    const int lr = m >> 1;
    aOff[i] = lr * 128 + ((((m & 1) << 6) | (16 * g)) ^ ((lr & 7) << 4));
    const int n = wc * 64 + i * 16 + r;
    const int lrn = n >> 1;
    bOff[i] = 8192 + lrn * 128 + ((((n & 1) << 6) | (16 * g)) ^ ((lrn & 7) << 4));
  }

  float4v acc[4][4] = {};
  auto compute = [&](int buf) {
    const char* sb = smem + buf * 16384;
    short8 a[4], b[4];
#pragma unroll
    for (int i = 0; i < 4; ++i) a[i] = *(const short8*)(sb + aOff[i]);
#pragma unroll
    for (int i = 0; i < 4; ++i) b[i] = *(const short8*)(sb + bOff[i]);
#pragma unroll
    for (int mi = 0; mi < 4; ++mi)
#pragma unroll
      for (int ni = 0; ni < 4; ++ni)
        acc[mi][ni] = MFMA16(a[mi], b[ni], acc[mi][ni]);
  };

  stage(0, 0);
  stage(1, 1);
#pragma unroll 1
  for (int t = 0; t < 10; ++t) {
    asm volatile("s_waitcnt vmcnt(4)" ::: "memory");
    __builtin_amdgcn_s_barrier();
    compute(t % 3);
    stage(t + 2, (t + 2) % 3);
  }
  asm volatile("s_waitcnt vmcnt(4)" ::: "memory");
  __builtin_amdgcn_s_barrier();
  compute(1);
  asm volatile("s_waitcnt vmcnt(0)" ::: "memory");
  __builtin_amdgcn_s_barrier();
  compute(2);

#pragma unroll
  for (int ni = 0; ni < 4; ++ni) {
    const int col = n0 + ni * 16 + r;
    const float bv = bv_n[ni];
#pragma unroll
    for (int mi = 0; mi < 4; ++mi) {
#pragma unroll
      for (int reg = 0; reg < 4; ++reg) {
        const int mg = m0 + mi * 16 + 4 * g + reg;
        out[mg * Dm + col] = acc[mi][ni][reg] + bv;
      }
    }
  }
}

extern "C" void kernel_launch(void* const* d_in, const int* in_sizes, int n_in,
                              void* d_out, int out_size, void* d_ws, size_t ws_size,
                              hipStream_t stream) {
  const float* x  = (const float*)d_in[0];
  const float* Wq = (const float*)d_in[1];
  const float* bq = (const float*)d_in[2];
  const float* Wk = (const float*)d_in[3];
  const float* bk = (const float*)d_in[4];
  const float* Wv = (const float*)d_in[5];
  const float* bv = (const float*)d_in[6];
  const float* Wo = (const float*)d_in[7];
  const float* bo = (const float*)d_in[8];
  float* out = (float*)d_out;

  char* ws = (char*)d_ws;
  short* Xb   = (short*)(ws);                  // 16384*384*2   = 12,582,912
  short* Wt   = (short*)(ws + 12582912);       // 1152*384*2    =    884,736
  float* bias = (float*)(ws + 13467648);       // 1152*4        =      4,608
  short* Wob  = (short*)(ws + 13472256);       // 384*384*2     =    294,912
  short* qkv  = (short*)(ws + 13767168);       // 16384*1152*2  = 37,748,736
  short* vt   = (short*)(ws + 51515904);       // 16*6*64*1024*2= 12,582,912
  short* ctx  = (short*)(ws + 64098816);       // 16384*384*2   = 12,582,912
  // total 76,681,728 bytes

  conv_x<<<Mtok * Dm / (256 * 8), 256, 0, stream>>>(x, Xb);
  conv_w<<<(NQKV * Dm + NQKV + Dm * Dm + 255) / 256, 256, 0, stream>>>(
      Wq, Wk, Wv, bq, bk, bv, Wo, Wt, bias, Wob);
  qkv_gemm<<<1152, 256, 0, stream>>>(Xb, Wt, bias, qkv, vt);
  attn<<<768, 256, 0, stream>>>(qkv, vt, ctx);
  out_gemm<<<384, 256, 0, stream>>>(ctx, Wob, bo, out);
}

// Round 11
// 94.393 us; speedup vs baseline: 1.1295x; 1.0417x over previous
//
#include <hip/hip_runtime.h>
#include <hip/hip_bf16.h>

typedef __attribute__((ext_vector_type(8))) short short8;
typedef __attribute__((ext_vector_type(4))) short short4v;
typedef __attribute__((ext_vector_type(4))) float float4v;
typedef __attribute__((ext_vector_type(2))) float float2v;
typedef __attribute__((ext_vector_type(4))) int int4v;

#define MFMA16(a,b,c) __builtin_amdgcn_mfma_f32_16x16x32_bf16((a),(b),(c),0,0,0)
#define EXP2(x) __builtin_amdgcn_exp2f(x)

static constexpr int Bz = 16, Sq = 1024, Dm = 384, Hh = 6, Dh = 64;
static constexpr int Mtok = Bz * Sq;     // 16384
static constexpr int NQKV = 1152;        // 3 * H * DH

__device__ __forceinline__ short f2bf(float f) {
  union { float f; unsigned u; } v; v.f = f;
  unsigned r = v.u + 0x7fffu + ((v.u >> 16) & 1u);  // RNE
  return (short)(r >> 16);
}

// packed f32x2 -> bf16x2 (lo = a, hi = b), RNE in HW
__device__ __forceinline__ unsigned cvtpk(float a, float b) {
  unsigned d;
  asm("v_cvt_pk_bf16_f32 %0, %1, %2" : "=v"(d) : "v"(a), "v"(b));
  return d;
}

__device__ __forceinline__ void gload16(const void* src, void* lds) {
  __builtin_amdgcn_global_load_lds(
      (const __attribute__((address_space(1))) unsigned int*)src,
      (__attribute__((address_space(3))) unsigned int*)lds, 16, 0, 0);
}

// kv-permutation within each 32-block: loc = 16hi+4grp+e -> 8grp+4hi+e.
// Makes each lane's PV B-fragment 16 CONTIGUOUS bytes -> single
// conflict-free ds_read_b128 in attn (verified R7: conflicts -> 0).
__device__ __forceinline__ int vperm(int s) {
  return (s & ~31) | ((s & 12) << 1) | ((s & 16) >> 2) | (s & 3);
}

// ---------------- prep: x->bf16 AND weight repack in one launch ----------------
__global__ __launch_bounds__(256) void prep(const float* __restrict__ x,
                                            const float* __restrict__ Wq,
                                            const float* __restrict__ Wk,
                                            const float* __restrict__ Wv,
                                            const float* __restrict__ bq,
                                            const float* __restrict__ bk,
                                            const float* __restrict__ bv,
                                            const float* __restrict__ Wo,
                                            short* __restrict__ xb,
                                            short* __restrict__ Wt,
                                            float* __restrict__ bias,
                                            short* __restrict__ Wob) {
  const float SCL = 0.125f * 1.44269504088896340736f;
  const int NX = Mtok * Dm / 8;        // 786432 vec8 units
  const int NW = NQKV * Dm;            // 442368
  const int idx = blockIdx.x * 256 + threadIdx.x;
  if (idx < NX) {
    const int i = idx * 8;
    float4v v0 = *(const float4v*)(x + i);
    float4v v1 = *(const float4v*)(x + i + 4);
    short8 o;
    o[0] = f2bf(v0[0]); o[1] = f2bf(v0[1]); o[2] = f2bf(v0[2]); o[3] = f2bf(v0[3]);
    o[4] = f2bf(v1[0]); o[5] = f2bf(v1[1]); o[6] = f2bf(v1[2]); o[7] = f2bf(v1[3]);
    *(short8*)(xb + i) = o;
    return;
  }
  const int i = idx - NX;
  if (i < NW) {
    const int c = i / Dm, d = i % Dm;
    const int p = c / 384, rr = c % 384;
    const int h = rr >> 6, dh = rr & 63;
    const float* W = (p == 0) ? Wq : ((p == 1) ? Wk : Wv);
    float w = W[(h * Dm + d) * Dh + dh];
    if (p == 0) w *= SCL;
    Wt[c * Dm + d] = f2bf(w);
  } else if (i < NW + NQKV) {
    const int c = i - NW;
    const int p = c / 384, rr = c % 384;
    const int h = rr >> 6, dh = rr & 63;
    const float* bb = (p == 0) ? bq : ((p == 1) ? bk : bv);
    float b = bb[h * Dh + dh];
    if (p == 0) b *= SCL;
    bias[c] = b;
  } else if (i < NW + NQKV + Dm * Dm) {
    const int j = i - NW - NQKV;
    Wob[j] = f2bf(Wo[j]);
  }
}

// ---------------- QKV GEMM v6: BK=32, 1-barrier 3-buf ----------------
__global__ __launch_bounds__(256) void qkv_gemm(const short* __restrict__ Xb,
                                                const short* __restrict__ Wt,
                                                const float* __restrict__ bias,
                                                short* __restrict__ qkv,
                                                short* __restrict__ vt) {
  __shared__ char smem[49152];  // 3 bufs x (8KB A + 8KB B)
  const int tid = threadIdx.x;
  const int wave = tid >> 6, lane = tid & 63;
  const int r = lane & 15, g = lane >> 4;
  const int wr = wave >> 1, wc = wave & 1;

  // XCD-chunked bijective swizzle: nwg = 1152 = 8*144
  const int flat = blockIdx.x;
  const int w = (flat & 7) * 144 + (flat >> 3);
  const int bx = w % 9, by = w / 9;
  const int bm0 = by * 128, bn0 = bx * 128;
  const int m0 = bm0 + wr * 64, n0 = bn0 + wc * 64;

  float bv_n[4];
#pragma unroll
  for (int ni = 0; ni < 4; ++ni) bv_n[ni] = bias[n0 + ni * 16 + r];
  asm volatile("s_waitcnt vmcnt(0)" ::: "memory");

  const char *aSrc0, *aSrc1, *bSrc0, *bSrc1;
  {
    const int o0 = tid * 16, o1 = 4096 + tid * 16;
    const int lr0 = o0 >> 7, cb0 = (o0 & 127) ^ ((lr0 & 7) << 4);
    const int lr1 = o1 >> 7, cb1 = (o1 & 127) ^ ((lr1 & 7) << 4);
    const int m_0 = 2 * lr0 + (cb0 >> 6), kb0 = cb0 & 63;
    const int m_1 = 2 * lr1 + (cb1 >> 6), kb1 = cb1 & 63;
    aSrc0 = (const char*)(Xb + (bm0 + m_0) * Dm) + kb0;
    aSrc1 = (const char*)(Xb + (bm0 + m_1) * Dm) + kb1;
    bSrc0 = (const char*)(Wt + (bn0 + m_0) * Dm) + kb0;
    bSrc1 = (const char*)(Wt + (bn0 + m_1) * Dm) + kb1;
  }
  auto stage = [&](int t, int buf) {
    char* base = smem + buf * 16384;
    const int kb = t * 64;
    gload16(aSrc0 + kb, base + wave * 1024);
    gload16(aSrc1 + kb, base + 4096 + wave * 1024);
    gload16(bSrc0 + kb, base + 8192 + wave * 1024);
    gload16(bSrc1 + kb, base + 12288 + wave * 1024);
  };

  int aOff[4], bOff[4];
#pragma unroll
  for (int i = 0; i < 4; ++i) {
    const int m = wr * 64 + i * 16 + r;
    const int lr = m >> 1;
    aOff[i] = lr * 128 + ((((m & 1) << 6) | (16 * g)) ^ ((lr & 7) << 4));
    const int n = wc * 64 + i * 16 + r;
    const int lrn = n >> 1;
    bOff[i] = 8192 + lrn * 128 + ((((n & 1) << 6) | (16 * g)) ^ ((lrn & 7) << 4));
  }

  float4v acc[4][4] = {};
  auto compute = [&](int buf) {
    const char* sb = smem + buf * 16384;
    short8 a[4], b[4];
#pragma unroll
    for (int i = 0; i < 4; ++i) a[i] = *(const short8*)(sb + aOff[i]);
#pragma unroll
    for (int i = 0; i < 4; ++i) b[i] = *(const short8*)(sb + bOff[i]);
#pragma unroll
    for (int mi = 0; mi < 4; ++mi)
#pragma unroll
      for (int ni = 0; ni < 4; ++ni)
        acc[mi][ni] = MFMA16(a[mi], b[ni], acc[mi][ni]);
  };

  stage(0, 0);
  stage(1, 1);
#pragma unroll 1
  for (int t = 0; t < 10; ++t) {  // 12 K-steps total
    asm volatile("s_waitcnt vmcnt(4)" ::: "memory");
    __builtin_amdgcn_s_barrier();
    compute(t % 3);
    stage(t + 2, (t + 2) % 3);
  }
  asm volatile("s_waitcnt vmcnt(4)" ::: "memory");
  __builtin_amdgcn_s_barrier();
  compute(1);
  asm volatile("s_waitcnt vmcnt(0)" ::: "memory");
  __builtin_amdgcn_s_barrier();
  compute(2);

#pragma unroll
  for (int ni = 0; ni < 4; ++ni) {
    const int col = n0 + ni * 16 + r;
    const int p = col / 384, rr2 = col % 384;
    const int h = rr2 >> 6, dh = rr2 & 63;
    const float bv = bv_n[ni];
#pragma unroll
    for (int mi = 0; mi < 4; ++mi) {
#pragma unroll
      for (int rp = 0; rp < 2; ++rp) {
        const unsigned u = cvtpk(acc[mi][ni][2 * rp] + bv,
                                 acc[mi][ni][2 * rp + 1] + bv);
        const int mg = m0 + mi * 16 + 4 * g + 2 * rp;
        if (p < 2) {
          qkv[mg * NQKV + col] = (short)u;
          qkv[(mg + 1) * NQKV + col] = (short)(u >> 16);
        } else {
          const int bb = mg >> 10, s = mg & 1023;
          const int sp = vperm(s);  // sp even -> 4B-aligned int store
          short* vp = vt + ((bb * Hh + h) * Dh + dh) * Sq;
          *(unsigned*)(vp + sp) = u;
        }
      }
    }
  }
}

// ---------------- attention v10: T15 cross-tile pipeline ----------------
// grid 768; 4 waves x 32 q-rows; KBLK=64; 3-buf 48KB, 1 barrier/tile.
// Iteration t: QK(t) MFMAs issued first, exp(t-1) VALU overlaps them,
// PV(t-1) from carried registers (s_prev, vf_prev). LDS access pattern
// identical to R10 (vf(t) read at iter t from buf(t)); only consumption
// is deferred one iteration via registers.
__global__ __launch_bounds__(256) void attn(const short* __restrict__ qkv,
                                            const short* __restrict__ vt,
                                            short* __restrict__ ctx) {
  __shared__ char smem[49152];  // 3 bufs x (8KB K + 8KB V)
  const int tid = threadIdx.x;
  const int wave = tid >> 6, lane = tid & 63;
  const int r = lane & 15, g = lane >> 4;
  const int xr = (r & 7) << 4;
  // XCD-chunked swizzle: nwg = 768 = 8*96
  const int flat = blockIdx.x;
  const int w = (flat & 7) * 96 + (flat >> 3);
  const int qb = w & 7, bh = w >> 3;
  const int b = bh / Hh, h = bh % Hh;
  const int tok0 = b * Sq;
  const int qw = qb * 128 + wave * 32;

  short8 qf[2][2];
#pragma unroll
  for (int f = 0; f < 2; ++f) {
    const short* qp = qkv + (tok0 + qw + 16 * f + r) * NQKV + h * Dh;
    qf[f][0] = *(const short8*)(qp + 8 * g);
    qf[f][1] = *(const short8*)(qp + 32 + 8 * g);
  }
  asm volatile("s_waitcnt vmcnt(0)" ::: "memory");  // drain Q before DMA counting

  const short* kg = qkv + tok0 * NQKV + 384 + h * Dh;  // K rows, stride NQKV
  const short* vg = vt + (b * Hh + h) * Dh * Sq;       // V^T rows (kv-permuted)

  const int o0 = wave * 2048 + lane * 16;
  const int row0 = o0 >> 7, cb0 = (o0 & 127) ^ ((row0 & 7) << 4);
  const int o1 = o0 + 1024;
  const int row1 = o1 >> 7, cb1 = (o1 & 127) ^ ((row1 & 7) << 4);

#define STAGE(T, BUFSEL)                                                        \
  {                                                                             \
    char* kb_ = smem + (BUFSEL) * 16384;                                        \
    const int kv_ = (T) * 64;                                                   \
    gload16((const char*)(kg + (kv_ + row0) * NQKV) + cb0, kb_ + wave * 2048);  \
    gload16((const char*)(vg + row0 * Sq + kv_) + cb0, kb_ + 8192 + wave * 2048);\
    gload16((const char*)(kg + (kv_ + row1) * NQKV) + cb1, kb_ + wave * 2048 + 1024);\
    gload16((const char*)(vg + row1 * Sq + kv_) + cb1, kb_ + 8192 + wave * 2048 + 1024);\
  }

  int kOff[4][2], vOff[4][2];
#pragma unroll
  for (int kt = 0; kt < 4; ++kt)
#pragma unroll
    for (int c = 0; c < 2; ++c)
      kOff[kt][c] = (16 * kt + r) * 128 + ((64 * c + 16 * g) ^ xr);
#pragma unroll
  for (int d = 0; d < 4; ++d)
#pragma unroll
    for (int h2 = 0; h2 < 2; ++h2)
      vOff[d][h2] = (16 * d + r) * 128 + ((64 * h2 + 16 * g) ^ xr);

  float4v acc[4][2] = {};
  float2v lsum2[2] = {};
  float4v sP[4][2];    // scores of previous tile (exp2 domain)
  short8 vfP[4][2];    // V fragments of previous tile

  auto loadKV = [&](int bufsel, short8 (&kf)[4][2], short8 (&vf)[4][2]) {
    const char* kb = smem + bufsel * 16384;
    const char* vb = kb + 8192;
#pragma unroll
    for (int kt = 0; kt < 4; ++kt) {
      kf[kt][0] = *(const short8*)(kb + kOff[kt][0]);
      kf[kt][1] = *(const short8*)(kb + kOff[kt][1]);
    }
#pragma unroll
    for (int d = 0; d < 4; ++d)
#pragma unroll
      for (int h2 = 0; h2 < 2; ++h2)
        vf[d][h2] = *(const short8*)(vb + vOff[d][h2]);
  };

  auto qkt = [&](const short8 (&kf)[4][2], float4v (&sD)[4][2]) {
    __builtin_amdgcn_s_setprio(1);
#pragma unroll
    for (int kt = 0; kt < 4; ++kt)
#pragma unroll
      for (int f = 0; f < 2; ++f) {
        float4v z = {};
        z = MFMA16(kf[kt][0], qf[f][0], z);
        z = MFMA16(kf[kt][1], qf[f][1], z);
        sD[kt][f] = z;
      }
    __builtin_amdgcn_s_setprio(0);
  };

  // exp + P-pack + PV for the PREVIOUS tile (consumes sP, vfP)
  auto softpv = [&]() {
    short8 pa[2][2];
#pragma unroll
    for (int f = 0; f < 2; ++f) {
      float2v ps2 = {};
#pragma unroll
      for (int h2 = 0; h2 < 2; ++h2) {
        float e0[4], e1[4];
#pragma unroll
        for (int j = 0; j < 4; ++j) {
          e0[j] = EXP2(sP[2 * h2][f][j]);
          e1[j] = EXP2(sP[2 * h2 + 1][f][j]);
        }
#pragma unroll
        for (int j = 0; j < 2; ++j) {
          float2v p0 = {e0[2 * j], e0[2 * j + 1]};
          float2v p1 = {e1[2 * j], e1[2 * j + 1]};
          ps2 += p0 + p1;  // v_pk_add_f32
        }
        int4v wv;
        wv[0] = (int)cvtpk(e0[0], e0[1]);
        wv[1] = (int)cvtpk(e0[2], e0[3]);
        wv[2] = (int)cvtpk(e1[0], e1[1]);
        wv[3] = (int)cvtpk(e1[2], e1[3]);
        pa[f][h2] = __builtin_bit_cast(short8, wv);
      }
      lsum2[f] += ps2;
    }
    __builtin_amdgcn_s_setprio(1);
#pragma unroll
    for (int d = 0; d < 4; ++d)
#pragma unroll
      for (int f = 0; f < 2; ++f) {
        acc[d][f] = MFMA16(pa[f][0], vfP[d][0], acc[d][f]);
        acc[d][f] = MFMA16(pa[f][1], vfP[d][1], acc[d][f]);
      }
    __builtin_amdgcn_s_setprio(0);
  };

  STAGE(0, 0)
  STAGE(1, 1)
  asm volatile("s_waitcnt vmcnt(4)" ::: "memory");
  __builtin_amdgcn_s_barrier();
  {  // prologue: tile 0 QK only
    short8 kf[4][2];
    loadKV(0, kf, vfP);
    qkt(kf, sP);
  }
  STAGE(2, 2)

#pragma unroll 1
  for (int t = 1; t <= 15; ++t) {
    if (t < 15) {
      asm volatile("s_waitcnt vmcnt(4)" ::: "memory");
    } else {
      asm volatile("s_waitcnt vmcnt(0)" ::: "memory");
    }
    __builtin_amdgcn_s_barrier();
    short8 kf[4][2], vfC[4][2];
    loadKV(t % 3, kf, vfC);
    float4v sC[4][2];
    qkt(kf, sC);      // MFMAs for tile t in flight...
    softpv();         // ...while VALU finishes tile t-1, then PV(t-1)
#pragma unroll
    for (int kt = 0; kt < 4; ++kt)
#pragma unroll
      for (int f = 0; f < 2; ++f) sP[kt][f] = sC[kt][f];
#pragma unroll
    for (int d = 0; d < 4; ++d)
#pragma unroll
      for (int h2 = 0; h2 < 2; ++h2) vfP[d][h2] = vfC[d][h2];
    if (t <= 13) STAGE(t + 2, (t + 2) % 3)
  }
  softpv();  // tile 15 finish

#pragma unroll
  for (int f = 0; f < 2; ++f) {
    float lsum = lsum2[f][0] + lsum2[f][1];
    lsum += __shfl_xor(lsum, 16);
    lsum += __shfl_xor(lsum, 32);
    float il[4];
#pragma unroll
    for (int reg = 0; reg < 4; ++reg) il[reg] = 1.f / __shfl(lsum, 4 * g + reg);
#pragma unroll
    for (int d = 0; d < 4; ++d) {
      short* cp = ctx + (tok0 + qw + 16 * f + 4 * g) * Dm + h * Dh + 16 * d + r;
#pragma unroll
      for (int reg = 0; reg < 4; ++reg)
        cp[reg * Dm] = f2bf(acc[d][f][reg] * il[reg]);
    }
  }
}

// ---------------- out-proj GEMM v5: BK=32, 1-barrier 3-buf ----------------
__global__ __launch_bounds__(256) void out_gemm(const short* __restrict__ ctx,
                                                const short* __restrict__ Wob,
                                                const float* __restrict__ bo,
                                                float* __restrict__ out) {
  __shared__ char smem[49152];
  const int tid = threadIdx.x;
  const int wave = tid >> 6, lane = tid & 63;
  const int r = lane & 15, g = lane >> 4;
  const int wr = wave >> 1, wc = wave & 1;

  // XCD-chunked bijective swizzle: nwg = 384 = 8*48
  const int flat = blockIdx.x;
  const int w = (flat & 7) * 48 + (flat >> 3);
  const int bx = w % 3, by = w / 3;
  const int bm0 = by * 128, bn0 = bx * 128;
  const int m0 = bm0 + wr * 64, n0 = bn0 + wc * 64;

  float bv_n[4];
#pragma unroll
  for (int ni = 0; ni < 4; ++ni) bv_n[ni] = bo[n0 + ni * 16 + r];
  asm volatile("s_waitcnt vmcnt(0)" ::: "memory");

  const char *aSrc0, *aSrc1, *bSrc0, *bSrc1;
  {
    const int o0 = tid * 16, o1 = 4096 + tid * 16;
    const int lr0 = o0 >> 7, cb0 = (o0 & 127) ^ ((lr0 & 7) << 4);
    const int lr1 = o1 >> 7, cb1 = (o1 & 127) ^ ((lr1 & 7) << 4);
    const int m_0 = 2 * lr0 + (cb0 >> 6), kb0 = cb0 & 63;
    const int m_1 = 2 * lr1 + (cb1 >> 6), kb1 = cb1 & 63;
    aSrc0 = (const char*)(ctx + (bm0 + m_0) * Dm) + kb0;
    aSrc1 = (const char*)(ctx + (bm0 + m_1) * Dm) + kb1;
    bSrc0 = (const char*)(Wob + (bn0 + m_0) * Dm) + kb0;
    bSrc1 = (const char*)(Wob + (bn0 + m_1) * Dm) + kb1;
  }
  auto stage = [&](int t, int buf) {
    char* base = smem + buf * 16384;
    const int kb = t * 64;
    gload16(aSrc0 + kb, base + wave * 1024);
    gload16(aSrc1 + kb, base + 4096 + wave * 1024);
    gload16(bSrc0 + kb, base + 8192 + wave * 1024);
    gload16(bSrc1 + kb, base + 12288 + wave * 1024);
  };

  int aOff[4], bOff[4];
#pragma unroll
  for (int i = 0; i < 4; ++i) {
    const int m = wr * 64 + i * 16 + r;
    const int lr = m >> 1;
    aOff[i] = lr * 128 + ((((m & 1) << 6) | (16 * g)) ^ ((lr & 7) << 4));
    const int n = wc * 64 + i * 16 + r;
    const int lrn = n >> 1;
    bOff[i] = 8192 + lrn * 128 + ((((n & 1) << 6) | (16 * g)) ^ ((lrn & 7) << 4));
  }

  float4v acc[4][4] = {};
  auto compute = [&](int buf) {
    const char* sb = smem + buf * 16384;
    short8 a[4], b[4];
#pragma unroll
    for (int i = 0; i < 4; ++i) a[i] = *(const short8*)(sb + aOff[i]);
#pragma unroll
    for (int i = 0; i < 4; ++i) b[i] = *(const short8*)(sb + bOff[i]);
#pragma unroll
    for (int mi = 0; mi < 4; ++mi)
#pragma unroll
      for (int ni = 0; ni < 4; ++ni)
        acc[mi][ni] = MFMA16(a[mi], b[ni], acc[mi][ni]);
  };

  stage(0, 0);
  stage(1, 1);
#pragma unroll 1
  for (int t = 0; t < 10; ++t) {
    asm volatile("s_waitcnt vmcnt(4)" ::: "memory");
    __builtin_amdgcn_s_barrier();
    compute(t % 3);
    stage(t + 2, (t + 2) % 3);
  }
  asm volatile("s_waitcnt vmcnt(4)" ::: "memory");
  __builtin_amdgcn_s_barrier();
  compute(1);
  asm volatile("s_waitcnt vmcnt(0)" ::: "memory");
  __builtin_amdgcn_s_barrier();
  compute(2);

#pragma unroll
  for (int ni = 0; ni < 4; ++ni) {
    const int col = n0 + ni * 16 + r;
    const float bv = bv_n[ni];
#pragma unroll
    for (int mi = 0; mi < 4; ++mi) {
#pragma unroll
      for (int reg = 0; reg < 4; ++reg) {
        const int mg = m0 + mi * 16 + 4 * g + reg;
        out[mg * Dm + col] = acc[mi][ni][reg] + bv;
      }
    }
  }
}

extern "C" void kernel_launch(void* const* d_in, const int* in_sizes, int n_in,
                              void* d_out, int out_size, void* d_ws, size_t ws_size,
                              hipStream_t stream) {
  const float* x  = (const float*)d_in[0];
  const float* Wq = (const float*)d_in[1];
  const float* bq = (const float*)d_in[2];
  const float* Wk = (const float*)d_in[3];
  const float* bk = (const float*)d_in[4];
  const float* Wv = (const float*)d_in[5];
  const float* bv = (const float*)d_in[6];
  const float* Wo = (const float*)d_in[7];
  const float* bo = (const float*)d_in[8];
  float* out = (float*)d_out;

  char* ws = (char*)d_ws;
  short* Xb   = (short*)(ws);                  // 16384*384*2   = 12,582,912
  short* Wt   = (short*)(ws + 12582912);       // 1152*384*2    =    884,736
  float* bias = (float*)(ws + 13467648);       // 1152*4        =      4,608
  short* Wob  = (short*)(ws + 13472256);       // 384*384*2     =    294,912
  short* qkv  = (short*)(ws + 13767168);       // 16384*1152*2  = 37,748,736
  short* vt   = (short*)(ws + 51515904);       // 16*6*64*1024*2= 12,582,912
  short* ctx  = (short*)(ws + 64098816);       // 16384*384*2   = 12,582,912
  // total 76,681,728 bytes

  const int prepN = Mtok * Dm / 8 + NQKV * Dm + NQKV + Dm * Dm;  // 1,377,408
  prep<<<(prepN + 255) / 256, 256, 0, stream>>>(x, Wq, Wk, Wv, bq, bk, bv, Wo,
                                                Xb, Wt, bias, Wob);
  qkv_gemm<<<1152, 256, 0, stream>>>(Xb, Wt, bias, qkv, vt);
  attn<<<768, 256, 0, stream>>>(qkv, vt, ctx);
  out_gemm<<<384, 256, 0, stream>>>(ctx, Wob, bo, out);
}